// Round 11
// baseline (132.733 us; speedup 1.0000x reference)
//
#include <hip/hip_runtime.h>
#include <hip/hip_fp16.h>
#include <math.h>

#define NN 30000
#define KK 32
#define FF 256
#define DD 128
#define NB16 1875   // 30000 / 16 exactly

typedef _Float16 f16x8 __attribute__((ext_vector_type(8)));
typedef float f32x4v __attribute__((ext_vector_type(4)));

__device__ __forceinline__ float seluf(float x) {
    const float scale = 1.0507009873554804934193349852946f;
    const float alpha = 1.6732632423543772848170429916717f;
    return x > 0.f ? scale * x : scale * alpha * expm1f(x);
}

__device__ __forceinline__ float waveReduceSum(float v) {
#pragma unroll
    for (int m = 1; m < 64; m <<= 1) v += __shfl_xor(v, m, 64);
    return v;
}

// -------- kernel 0: transposed f16 weight tables ---------------------------
__global__ __launch_bounds__(256) void k_prep(
    const float* __restrict__ W, const float* __restrict__ M,
    _Float16* __restrict__ Wt, _Float16* __restrict__ Lt)
{
    const int b = blockIdx.x, t = threadIdx.x;
    if (b < 128) {
        Wt[b * FF + t] = (_Float16)W[t * DD + b];
    } else if (t < 128) {
        const int c = b - 128, k = t;
        const float v = (k == 0 && c == 0) ? 1.f
                      : ((k >= 1 && c >= 1) ? M[(k - 1) * 127 + (c - 1)] : 0.f);
        Lt[c * DD + k] = (_Float16)v;
    }
}

// -------- kernel 1: table = msg_aux(normalize(expmap(selu(x@W+b))) @ lw) ---
// 4 waves / 16 rows per block; wave wv_ owns cols wv_*32..+31 (2 n-tiles).
// Phase 1: single-f16 A (x@W); phase 2: hi/lo exact-A msg MFMA from LDS.
__global__ __launch_bounds__(256) void k_lin_exp_msg(
    const float* __restrict__ x, const _Float16* __restrict__ Wt,
    const float* __restrict__ b, const _Float16* __restrict__ Lt,
    __half* __restrict__ table)
{
    __shared__ float hs[16][132];
    __shared__ float red[4][16];
    __shared__ float m0s[16];
    const int wv_ = threadIdx.x >> 6;
    const int lane = threadIdx.x & 63;
    const int g = lane >> 4, c16 = lane & 15;
    const int baseRow = blockIdx.x * 16;
    const int nb = wv_ * 2;            // n-tile base: cols nb*16 .. nb*16+31
    const int arow = baseRow + c16;    // always < NN (30000 = 16*1875)

    // ---- phase 1: h = normalize(expmap(selu(x@W+b))) ----
    f16x8 ahi[8];
    const float4* xp = (const float4*)(x + (size_t)arow * FF) + g * 2;
#pragma unroll
    for (int c = 0; c < 2; ++c) {
        float4 f[8];
#pragma unroll
        for (int kk = 0; kk < 4; ++kk) {
            f[2 * kk]     = xp[(c * 4 + kk) * 8];
            f[2 * kk + 1] = xp[(c * 4 + kk) * 8 + 1];
        }
#pragma unroll
        for (int kk = 0; kk < 4; ++kk) {
            const int ks = c * 4 + kk;
            const float q[8] = {f[2 * kk].x, f[2 * kk].y, f[2 * kk].z, f[2 * kk].w,
                                f[2 * kk + 1].x, f[2 * kk + 1].y, f[2 * kk + 1].z, f[2 * kk + 1].w};
#pragma unroll
            for (int j = 0; j < 8; ++j) ahi[ks][j] = (_Float16)q[j];
        }
    }

    f32x4v acc[2];
    acc[0] = acc[1] = f32x4v{0.f, 0.f, 0.f, 0.f};
#pragma unroll
    for (int ks = 0; ks < 8; ++ks) {
#pragma unroll
        for (int n = 0; n < 2; ++n) {
            const f16x8 bh = *(const f16x8*)(Wt + (size_t)((nb + n) * 16 + c16) * FF + ks * 32 + g * 8);
            acc[n] = __builtin_amdgcn_mfma_f32_16x16x32_f16(ahi[ks], bh, acc[n], 0, 0, 0);
        }
    }

    float bias[2];
#pragma unroll
    for (int n = 0; n < 2; ++n) bias[n] = b[(nb + n) * 16 + c16];

    float vv[4][2];
#pragma unroll
    for (int r = 0; r < 4; ++r) {
        float part = 0.f;
#pragma unroll
        for (int n = 0; n < 2; ++n) {
            vv[r][n] = seluf(acc[n][r] + bias[n]);
            float sq = vv[r][n] * vv[r][n];
            if (wv_ == 0 && n == 0 && c16 == 0) sq = 0.f;   // exclude d=0
            part += sq;
        }
#pragma unroll
        for (int m = 1; m < 16; m <<= 1) part += __shfl_xor(part, m, 64);
        if (c16 == 0) red[wv_][4 * g + r] = part;
    }
    __syncthreads();
#pragma unroll
    for (int r = 0; r < 4; ++r) {
        const int lrow = 4 * g + r;
        const float ldv = red[0][lrow] + red[1][lrow] + red[2][lrow] + red[3][lrow];
        const float nd = sqrtf(fmaxf(ldv + 1e-9f, 1e-10f));
        const float t  = fminf(nd, 1.0f);
        const float sc = sinhf(t) / nd;
        const float tm = sqrtf(1.f + sc * sc * ldv);
#pragma unroll
        for (int n = 0; n < 2; ++n) {
            const float o = (wv_ == 0 && n == 0 && c16 == 0) ? tm : sc * vv[r][n];
            hs[lrow][(nb + n) * 16 + c16] = o;
        }
    }
    __syncthreads();

    // ---- phase 2: msg = h @ lw (exact A via hi/lo); Klein + f-header ----
    f16x8 mhi[4], mlo[4];
#pragma unroll
    for (int ks = 0; ks < 4; ++ks) {
        const float* hp = &hs[c16][ks * 32 + g * 8];
        const float4 f0 = *(const float4*)hp;
        const float4 f1 = *(const float4*)(hp + 4);
        const float q[8] = {f0.x, f0.y, f0.z, f0.w, f1.x, f1.y, f1.z, f1.w};
#pragma unroll
        for (int j = 0; j < 8; ++j) {
            mhi[ks][j] = (_Float16)q[j];
            mlo[ks][j] = (_Float16)(q[j] - (float)mhi[ks][j]);
        }
    }

    acc[0] = acc[1] = f32x4v{0.f, 0.f, 0.f, 0.f};
#pragma unroll
    for (int ks = 0; ks < 4; ++ks) {
#pragma unroll
        for (int n = 0; n < 2; ++n) {
            const f16x8 bh = *(const f16x8*)(Lt + (size_t)((nb + n) * 16 + c16) * DD + ks * 32 + g * 8);
            acc[n] = __builtin_amdgcn_mfma_f32_16x16x32_f16(mhi[ks], bh, acc[n], 0, 0, 0);
            acc[n] = __builtin_amdgcn_mfma_f32_16x16x32_f16(mlo[ks], bh, acc[n], 0, 0, 0);
        }
    }

#pragma unroll
    for (int r = 0; r < 4; ++r) {
        float part = 0.f;
#pragma unroll
        for (int n = 0; n < 2; ++n) {
            float sq = acc[n][r] * acc[n][r];
            if (wv_ == 0 && n == 0 && c16 == 0) sq = 0.f;   // time slot
            part += sq;
        }
#pragma unroll
        for (int m = 1; m < 16; m <<= 1) part += __shfl_xor(part, m, 64);
        if (c16 == 0) red[wv_][4 * g + r] = part;
        if (wv_ == 0 && c16 == 0) m0s[4 * g + r] = acc[0][r];
    }
    __syncthreads();
#pragma unroll
    for (int r = 0; r < 4; ++r) {
        const int lrow = 4 * g + r;
        const int row = baseRow + lrow;
        const float rn = 1.f / m0s[lrow];
        const float sum2 = red[0][lrow] + red[1][lrow] + red[2][lrow] + red[3][lrow];
        float kn = sum2 * rn * rn;
        kn = fminf(fmaxf(kn, 0.f), 0.9f);
        const float fh = 1.f / sqrtf(1.f - kn);
#pragma unroll
        for (int n = 0; n < 2; ++n) {
            const float val = (wv_ == 0 && n == 0 && c16 == 0) ? fh : acc[n][r] * rn;
            table[(size_t)row * DD + (nb + n) * 16 + c16] = __float2half(val);
        }
    }
}

// -------- kernel 2: fp16 gather table = aux(h @ lw) via MFMA (layer 1) -----
// 4 waves / 16 rows per block; wave owns 32 cols; hi/lo exact A.
__global__ __launch_bounds__(256) void k_msg_aux(
    const float* __restrict__ h, const _Float16* __restrict__ Lt,
    __half* __restrict__ table)
{
    __shared__ float red[4][16];
    __shared__ float m0s[16];
    const int wv_ = threadIdx.x >> 6;
    const int lane = threadIdx.x & 63;
    const int g = lane >> 4, c16 = lane & 15;
    const int baseRow = blockIdx.x * 16;
    const int nb = wv_ * 2;
    const int arow = baseRow + c16;

    float4 f[8];
    const float4* hp = (const float4*)(h + (size_t)arow * DD) + g * 2;
#pragma unroll
    for (int ks = 0; ks < 4; ++ks) {
        f[2 * ks]     = hp[ks * 8];
        f[2 * ks + 1] = hp[ks * 8 + 1];
    }
    f16x8 ahi[4], alo[4];
#pragma unroll
    for (int ks = 0; ks < 4; ++ks) {
        const float q[8] = {f[2 * ks].x, f[2 * ks].y, f[2 * ks].z, f[2 * ks].w,
                            f[2 * ks + 1].x, f[2 * ks + 1].y, f[2 * ks + 1].z, f[2 * ks + 1].w};
#pragma unroll
        for (int j = 0; j < 8; ++j) {
            ahi[ks][j] = (_Float16)q[j];
            alo[ks][j] = (_Float16)(q[j] - (float)ahi[ks][j]);
        }
    }

    f32x4v acc[2];
    acc[0] = acc[1] = f32x4v{0.f, 0.f, 0.f, 0.f};
#pragma unroll
    for (int ks = 0; ks < 4; ++ks) {
#pragma unroll
        for (int n = 0; n < 2; ++n) {
            const f16x8 bh = *(const f16x8*)(Lt + (size_t)((nb + n) * 16 + c16) * DD + ks * 32 + g * 8);
            acc[n] = __builtin_amdgcn_mfma_f32_16x16x32_f16(ahi[ks], bh, acc[n], 0, 0, 0);
            acc[n] = __builtin_amdgcn_mfma_f32_16x16x32_f16(alo[ks], bh, acc[n], 0, 0, 0);
        }
    }

#pragma unroll
    for (int r = 0; r < 4; ++r) {
        float part = 0.f;
#pragma unroll
        for (int n = 0; n < 2; ++n) {
            float sq = acc[n][r] * acc[n][r];
            if (wv_ == 0 && n == 0 && c16 == 0) sq = 0.f;
            part += sq;
        }
#pragma unroll
        for (int m = 1; m < 16; m <<= 1) part += __shfl_xor(part, m, 64);
        if (c16 == 0) red[wv_][4 * g + r] = part;
        if (wv_ == 0 && c16 == 0) m0s[4 * g + r] = acc[0][r];
    }
    __syncthreads();
#pragma unroll
    for (int r = 0; r < 4; ++r) {
        const int lrow = 4 * g + r;
        const int row = baseRow + lrow;
        const float rn = 1.f / m0s[lrow];
        const float sum2 = red[0][lrow] + red[1][lrow] + red[2][lrow] + red[3][lrow];
        float kn = sum2 * rn * rn;
        kn = fminf(fmaxf(kn, 0.f), 0.9f);
        const float fh = 1.f / sqrtf(1.f - kn);
#pragma unroll
        for (int n = 0; n < 2; ++n) {
            const float val = (wv_ == 0 && n == 0 && c16 == 0) ? fh : acc[n][r] * rn;
            table[(size_t)row * DD + (nb + n) * 16 + c16] = __float2half(val);
        }
    }
}

// -------- kernel 3: gather + weighted mean + activation + normalize --------
// one wave per node; all 32 row-gathers prefetched into registers.
__global__ __launch_bounds__(256) void k_layer(
    const __half* __restrict__ table, const int* __restrict__ adj,
    const float* __restrict__ w, float* __restrict__ out)
{
    const int wave = threadIdx.x >> 6;
    const int lane = threadIdx.x & 63;
    const int node = blockIdx.x * 4 + wave;

    const int   av = adj[node * KK + (lane & 31)];
    const float wv = w[node * KK + (lane & 31)];

    unsigned int vbits[32];
#pragma unroll
    for (int j = 0; j < KK; ++j) {
        const int idx = __shfl(av, j, 64);
        vbits[j] = *(const unsigned int*)(table + (size_t)idx * DD + lane * 2);
    }

    const float f  = __half2float(table[(size_t)av * DD]);
    const float lam = wv * f;
    float ls = lam;
#pragma unroll
    for (int m = 1; m < 32; m <<= 1) ls += __shfl_xor(ls, m, 64);

    float km0 = 0.f, km1 = 0.f;
#pragma unroll
    for (int j = 0; j < KK; ++j) {
        const float cj = __shfl(lam, j, 64);
        const __half2 hh = *(const __half2*)&vbits[j];
        const float2 v = __half22float2(hh);
        km0 = fmaf(cj, v.x, km0);   // lane0.x holds f-header, masked below
        km1 = fmaf(cj, v.y, km1);
    }
    const float rl = 1.f / ls;
    const float m0 = km0 * rl;
    const float m1 = km1 * rl;
    float c2 = (lane ? m0 * m0 : 0.f) + m1 * m1;
    const float kn2 = fminf(waveReduceSum(c2), 0.9f);
    const float invs = 1.f / sqrtf(1.f - kn2);
    const float pd = invs + 1.f;
    const float p0 = lane ? seluf(m0 * invs / pd) : 0.f;
    const float p1 = seluf(m1 * invs / pd);
    float pc = p0 * p0 + p1 * p1;
    const float pn = waveReduceSum(pc);
    const float rdn = 1.f / (1.f - pn + 1e-6f);
    const float tm = sqrtf(1.f + 4.f * pn * rdn * rdn);
    float2 o;
    o.x = lane ? 2.f * p0 * rdn : tm;
    o.y = 2.f * p1 * rdn;
    *(float2*)(out + (size_t)node * DD + lane * 2) = o;
}

extern "C" void kernel_launch(void* const* d_in, const int* in_sizes, int n_in,
                              void* d_out, int out_size, void* d_ws, size_t ws_size,
                              hipStream_t stream) {
    const float* x     = (const float*)d_in[0];
    const int*   adj   = (const int*)d_in[1];
    const float* w     = (const float*)d_in[2];
    const float* lin_W = (const float*)d_in[3];
    const float* lin_b = (const float*)d_in[4];
    const float* M     = (const float*)d_in[5];
    float*  h     = (float*)d_out;                 // N*D fp32 (scratch + final)
    char*   ws    = (char*)d_ws;
    __half*   table = (__half*)ws;                 // 7,680,000 B
    _Float16* Wt    = (_Float16*)(ws + 7680000);   //    65,536 B
    _Float16* Lt    = (_Float16*)(ws + 7745536);   //    32,768 B

    k_prep<<<256, 256, 0, stream>>>(lin_W, M, Wt, Lt);
    // layer 0 table directly from x (h stays in LDS)
    k_lin_exp_msg<<<NB16, 256, 0, stream>>>(x, Wt, lin_b, Lt, table);
    k_layer<<<NN / 4, 256, 0, stream>>>(table, adj, w, h);
    // layer 1
    k_msg_aux<<<NB16, 256, 0, stream>>>(h, Lt, table);
    k_layer<<<NN / 4, 256, 0, stream>>>(table, adj, w, h);
}

// Round 12
// 119.454 us; speedup vs baseline: 1.1112x; 1.1112x over previous
//
#include <hip/hip_runtime.h>
#include <hip/hip_fp16.h>
#include <math.h>

#define NN 30000
#define KK 32
#define FF 256
#define DD 128
#define NB16 1875   // 30000 / 16 exactly
#define SA 268      // padded f16 row stride for LDS fragment arrays

typedef _Float16 f16x8 __attribute__((ext_vector_type(8)));
typedef float f32x4v __attribute__((ext_vector_type(4)));

__device__ __forceinline__ float seluf(float x) {
    const float scale = 1.0507009873554804934193349852946f;
    const float alpha = 1.6732632423543772848170429916717f;
    return x > 0.f ? scale * x : scale * alpha * expm1f(x);
}

__device__ __forceinline__ float waveReduceSum(float v) {
#pragma unroll
    for (int m = 1; m < 64; m <<= 1) v += __shfl_xor(v, m, 64);
    return v;
}

// -------- kernel 0: transposed f16 weight tables ---------------------------
__global__ __launch_bounds__(256) void k_prep(
    const float* __restrict__ W, const float* __restrict__ M,
    _Float16* __restrict__ Wt, _Float16* __restrict__ Lt)
{
    const int b = blockIdx.x, t = threadIdx.x;
    if (b < 128) {
        Wt[b * FF + t] = (_Float16)W[t * DD + b];
    } else if (t < 128) {
        const int c = b - 128, k = t;
        const float v = (k == 0 && c == 0) ? 1.f
                      : ((k >= 1 && c >= 1) ? M[(k - 1) * 127 + (c - 1)] : 0.f);
        Lt[c * DD + k] = (_Float16)v;
    }
}

// -------- kernel 1: table = msg_aux(normalize(expmap(selu(x@W+b))) @ lw) ---
// 4 waves / 16 rows; wave owns 32 cols (2 n-tiles). Cooperative LDS A-staging
// (each wave converts its k-slice once), explicit B-fragment hoisting.
__global__ __launch_bounds__(256) void k_lin_exp_msg(
    const float* __restrict__ x, const _Float16* __restrict__ Wt,
    const float* __restrict__ b, const _Float16* __restrict__ Lt,
    __half* __restrict__ table)
{
    __shared__ _Float16 as_[16][SA];    // x in f16, [row][k]
    __shared__ _Float16 hhi[16][SA];    // h hi part
    __shared__ _Float16 hlo[16][SA];    // h lo part (exact split)
    __shared__ float red[4][16];
    __shared__ float m0s[16];
    const int wv_ = threadIdx.x >> 6;
    const int lane = threadIdx.x & 63;
    const int g = lane >> 4, c16 = lane & 15;
    const int baseRow = blockIdx.x * 16;
    const int nb = wv_ * 2;
    const int arow = baseRow + c16;   // < NN always

    // ---- phase 0: cooperative x -> f16 staging (wave wv_: ks = 2wv_,2wv_+1)
    {
        const float4* xp = (const float4*)(x + (size_t)arow * FF);
#pragma unroll
        for (int i = 0; i < 2; ++i) {
            const int ks = wv_ * 2 + i;
            const float4 f0 = xp[ks * 8 + g * 2];
            const float4 f1 = xp[ks * 8 + g * 2 + 1];
            const float q[8] = {f0.x, f0.y, f0.z, f0.w, f1.x, f1.y, f1.z, f1.w};
            f16x8 a;
#pragma unroll
            for (int j = 0; j < 8; ++j) a[j] = (_Float16)q[j];
            *(f16x8*)&as_[c16][ks * 32 + g * 8] = a;
        }
    }
    __syncthreads();

    // ---- phase 1: h-GEMM. Hoist all B frags, then LDS A frags, then MFMA.
    f16x8 bw0[8], bw1[8];
#pragma unroll
    for (int ks = 0; ks < 8; ++ks) {
        bw0[ks] = *(const f16x8*)(Wt + (size_t)((nb + 0) * 16 + c16) * FF + ks * 32 + g * 8);
        bw1[ks] = *(const f16x8*)(Wt + (size_t)((nb + 1) * 16 + c16) * FF + ks * 32 + g * 8);
    }
    f16x8 af[8];
#pragma unroll
    for (int ks = 0; ks < 8; ++ks)
        af[ks] = *(const f16x8*)&as_[c16][ks * 32 + g * 8];

    f32x4v acc[2];
    acc[0] = acc[1] = f32x4v{0.f, 0.f, 0.f, 0.f};
#pragma unroll
    for (int ks = 0; ks < 8; ++ks) {
        acc[0] = __builtin_amdgcn_mfma_f32_16x16x32_f16(af[ks], bw0[ks], acc[0], 0, 0, 0);
        acc[1] = __builtin_amdgcn_mfma_f32_16x16x32_f16(af[ks], bw1[ks], acc[1], 0, 0, 0);
    }

    float bias[2];
#pragma unroll
    for (int n = 0; n < 2; ++n) bias[n] = b[(nb + n) * 16 + c16];

    float vv[4][2];
#pragma unroll
    for (int r = 0; r < 4; ++r) {
        float part = 0.f;
#pragma unroll
        for (int n = 0; n < 2; ++n) {
            vv[r][n] = seluf(acc[n][r] + bias[n]);
            float sq = vv[r][n] * vv[r][n];
            if (wv_ == 0 && n == 0 && c16 == 0) sq = 0.f;   // exclude d=0
            part += sq;
        }
#pragma unroll
        for (int m = 1; m < 16; m <<= 1) part += __shfl_xor(part, m, 64);
        if (c16 == 0) red[wv_][4 * g + r] = part;
    }
    __syncthreads();
    // epilogue: expmap+normalize; write h as exact hi/lo f16 pair to LDS
#pragma unroll
    for (int r = 0; r < 4; ++r) {
        const int lrow = 4 * g + r;
        const float ldv = red[0][lrow] + red[1][lrow] + red[2][lrow] + red[3][lrow];
        const float nd = sqrtf(fmaxf(ldv + 1e-9f, 1e-10f));
        const float t  = fminf(nd, 1.0f);
        const float sc = sinhf(t) / nd;
        const float tm = sqrtf(1.f + sc * sc * ldv);
#pragma unroll
        for (int n = 0; n < 2; ++n) {
            const int col = (nb + n) * 16 + c16;
            const float o = (wv_ == 0 && n == 0 && c16 == 0) ? tm : sc * vv[r][n];
            const _Float16 hi = (_Float16)o;
            hhi[lrow][col] = hi;
            hlo[lrow][col] = (_Float16)(o - (float)hi);
        }
    }
    __syncthreads();

    // ---- phase 2: msg = h @ lw (exact A via hi/lo frags from LDS) ----
    f16x8 bl0[4], bl1[4];
#pragma unroll
    for (int ks = 0; ks < 4; ++ks) {
        bl0[ks] = *(const f16x8*)(Lt + (size_t)((nb + 0) * 16 + c16) * DD + ks * 32 + g * 8);
        bl1[ks] = *(const f16x8*)(Lt + (size_t)((nb + 1) * 16 + c16) * DD + ks * 32 + g * 8);
    }
    f16x8 mh[4], ml[4];
#pragma unroll
    for (int ks = 0; ks < 4; ++ks) {
        mh[ks] = *(const f16x8*)&hhi[c16][ks * 32 + g * 8];
        ml[ks] = *(const f16x8*)&hlo[c16][ks * 32 + g * 8];
    }
    acc[0] = acc[1] = f32x4v{0.f, 0.f, 0.f, 0.f};
#pragma unroll
    for (int ks = 0; ks < 4; ++ks) {
        acc[0] = __builtin_amdgcn_mfma_f32_16x16x32_f16(mh[ks], bl0[ks], acc[0], 0, 0, 0);
        acc[0] = __builtin_amdgcn_mfma_f32_16x16x32_f16(ml[ks], bl0[ks], acc[0], 0, 0, 0);
        acc[1] = __builtin_amdgcn_mfma_f32_16x16x32_f16(mh[ks], bl1[ks], acc[1], 0, 0, 0);
        acc[1] = __builtin_amdgcn_mfma_f32_16x16x32_f16(ml[ks], bl1[ks], acc[1], 0, 0, 0);
    }

#pragma unroll
    for (int r = 0; r < 4; ++r) {
        float part = 0.f;
#pragma unroll
        for (int n = 0; n < 2; ++n) {
            float sq = acc[n][r] * acc[n][r];
            if (wv_ == 0 && n == 0 && c16 == 0) sq = 0.f;   // time slot
            part += sq;
        }
#pragma unroll
        for (int m = 1; m < 16; m <<= 1) part += __shfl_xor(part, m, 64);
        if (c16 == 0) red[wv_][4 * g + r] = part;
        if (wv_ == 0 && c16 == 0) m0s[4 * g + r] = acc[0][r];
    }
    __syncthreads();
#pragma unroll
    for (int r = 0; r < 4; ++r) {
        const int lrow = 4 * g + r;
        const int row = baseRow + lrow;
        const float rn = 1.f / m0s[lrow];
        const float sum2 = red[0][lrow] + red[1][lrow] + red[2][lrow] + red[3][lrow];
        float kn = sum2 * rn * rn;
        kn = fminf(fmaxf(kn, 0.f), 0.9f);
        const float fh = 1.f / sqrtf(1.f - kn);
#pragma unroll
        for (int n = 0; n < 2; ++n) {
            const float val = (wv_ == 0 && n == 0 && c16 == 0) ? fh : acc[n][r] * rn;
            table[(size_t)row * DD + (nb + n) * 16 + c16] = __float2half(val);
        }
    }
}

// -------- kernel 2: fp16 gather table = aux(h @ lw) via MFMA (layer 1) -----
// Cooperative hi/lo staging (wave wv_ converts ks=wv_), B-hoist, 4 waves.
__global__ __launch_bounds__(256) void k_msg_aux(
    const float* __restrict__ h, const _Float16* __restrict__ Lt,
    __half* __restrict__ table)
{
    __shared__ _Float16 hhi[16][SA];
    __shared__ _Float16 hlo[16][SA];
    __shared__ float red[4][16];
    __shared__ float m0s[16];
    const int wv_ = threadIdx.x >> 6;
    const int lane = threadIdx.x & 63;
    const int g = lane >> 4, c16 = lane & 15;
    const int baseRow = blockIdx.x * 16;
    const int nb = wv_ * 2;
    const int arow = baseRow + c16;

    // phase 0: cooperative h -> hi/lo staging (wave wv_ handles ks = wv_)
    {
        const float4* hp = (const float4*)(h + (size_t)arow * DD);
        const int ks = wv_;
        const float4 f0 = hp[ks * 8 + g * 2];
        const float4 f1 = hp[ks * 8 + g * 2 + 1];
        const float q[8] = {f0.x, f0.y, f0.z, f0.w, f1.x, f1.y, f1.z, f1.w};
        f16x8 hi, lo;
#pragma unroll
        for (int j = 0; j < 8; ++j) {
            hi[j] = (_Float16)q[j];
            lo[j] = (_Float16)(q[j] - (float)hi[j]);
        }
        *(f16x8*)&hhi[c16][ks * 32 + g * 8] = hi;
        *(f16x8*)&hlo[c16][ks * 32 + g * 8] = lo;
    }
    __syncthreads();

    f16x8 bl0[4], bl1[4];
#pragma unroll
    for (int ks = 0; ks < 4; ++ks) {
        bl0[ks] = *(const f16x8*)(Lt + (size_t)((nb + 0) * 16 + c16) * DD + ks * 32 + g * 8);
        bl1[ks] = *(const f16x8*)(Lt + (size_t)((nb + 1) * 16 + c16) * DD + ks * 32 + g * 8);
    }
    f16x8 mh[4], ml[4];
#pragma unroll
    for (int ks = 0; ks < 4; ++ks) {
        mh[ks] = *(const f16x8*)&hhi[c16][ks * 32 + g * 8];
        ml[ks] = *(const f16x8*)&hlo[c16][ks * 32 + g * 8];
    }
    f32x4v acc[2];
    acc[0] = acc[1] = f32x4v{0.f, 0.f, 0.f, 0.f};
#pragma unroll
    for (int ks = 0; ks < 4; ++ks) {
        acc[0] = __builtin_amdgcn_mfma_f32_16x16x32_f16(mh[ks], bl0[ks], acc[0], 0, 0, 0);
        acc[0] = __builtin_amdgcn_mfma_f32_16x16x32_f16(ml[ks], bl0[ks], acc[0], 0, 0, 0);
        acc[1] = __builtin_amdgcn_mfma_f32_16x16x32_f16(mh[ks], bl1[ks], acc[1], 0, 0, 0);
        acc[1] = __builtin_amdgcn_mfma_f32_16x16x32_f16(ml[ks], bl1[ks], acc[1], 0, 0, 0);
    }

#pragma unroll
    for (int r = 0; r < 4; ++r) {
        float part = 0.f;
#pragma unroll
        for (int n = 0; n < 2; ++n) {
            float sq = acc[n][r] * acc[n][r];
            if (wv_ == 0 && n == 0 && c16 == 0) sq = 0.f;
            part += sq;
        }
#pragma unroll
        for (int m = 1; m < 16; m <<= 1) part += __shfl_xor(part, m, 64);
        if (c16 == 0) red[wv_][4 * g + r] = part;
        if (wv_ == 0 && c16 == 0) m0s[4 * g + r] = acc[0][r];
    }
    __syncthreads();
#pragma unroll
    for (int r = 0; r < 4; ++r) {
        const int lrow = 4 * g + r;
        const int row = baseRow + lrow;
        const float rn = 1.f / m0s[lrow];
        const float sum2 = red[0][lrow] + red[1][lrow] + red[2][lrow] + red[3][lrow];
        float kn = sum2 * rn * rn;
        kn = fminf(fmaxf(kn, 0.f), 0.9f);
        const float fh = 1.f / sqrtf(1.f - kn);
#pragma unroll
        for (int n = 0; n < 2; ++n) {
            const float val = (wv_ == 0 && n == 0 && c16 == 0) ? fh : acc[n][r] * rn;
            table[(size_t)row * DD + (nb + n) * 16 + c16] = __float2half(val);
        }
    }
}

// -------- kernel 3: gather + weighted mean + activation + normalize --------
__global__ __launch_bounds__(256) void k_layer(
    const __half* __restrict__ table, const int* __restrict__ adj,
    const float* __restrict__ w, float* __restrict__ out)
{
    const int wave = threadIdx.x >> 6;
    const int lane = threadIdx.x & 63;
    const int node = blockIdx.x * 4 + wave;

    const int   av = adj[node * KK + (lane & 31)];
    const float wv = w[node * KK + (lane & 31)];

    unsigned int vbits[32];
#pragma unroll
    for (int j = 0; j < KK; ++j) {
        const int idx = __shfl(av, j, 64);
        vbits[j] = *(const unsigned int*)(table + (size_t)idx * DD + lane * 2);
    }

    const float f  = __half2float(table[(size_t)av * DD]);
    const float lam = wv * f;
    float ls = lam;
#pragma unroll
    for (int m = 1; m < 32; m <<= 1) ls += __shfl_xor(ls, m, 64);

    float km0 = 0.f, km1 = 0.f;
#pragma unroll
    for (int j = 0; j < KK; ++j) {
        const float cj = __shfl(lam, j, 64);
        const __half2 hh = *(const __half2*)&vbits[j];
        const float2 v = __half22float2(hh);
        km0 = fmaf(cj, v.x, km0);   // lane0.x holds f-header, masked below
        km1 = fmaf(cj, v.y, km1);
    }
    const float rl = 1.f / ls;
    const float m0 = km0 * rl;
    const float m1 = km1 * rl;
    float c2 = (lane ? m0 * m0 : 0.f) + m1 * m1;
    const float kn2 = fminf(waveReduceSum(c2), 0.9f);
    const float invs = 1.f / sqrtf(1.f - kn2);
    const float pd = invs + 1.f;
    const float p0 = lane ? seluf(m0 * invs / pd) : 0.f;
    const float p1 = seluf(m1 * invs / pd);
    float pc = p0 * p0 + p1 * p1;
    const float pn = waveReduceSum(pc);
    const float rdn = 1.f / (1.f - pn + 1e-6f);
    const float tm = sqrtf(1.f + 4.f * pn * rdn * rdn);
    float2 o;
    o.x = lane ? 2.f * p0 * rdn : tm;
    o.y = 2.f * p1 * rdn;
    *(float2*)(out + (size_t)node * DD + lane * 2) = o;
}

extern "C" void kernel_launch(void* const* d_in, const int* in_sizes, int n_in,
                              void* d_out, int out_size, void* d_ws, size_t ws_size,
                              hipStream_t stream) {
    const float* x     = (const float*)d_in[0];
    const int*   adj   = (const int*)d_in[1];
    const float* w     = (const float*)d_in[2];
    const float* lin_W = (const float*)d_in[3];
    const float* lin_b = (const float*)d_in[4];
    const float* M     = (const float*)d_in[5];
    float*  h     = (float*)d_out;                 // N*D fp32 (scratch + final)
    char*   ws    = (char*)d_ws;
    __half*   table = (__half*)ws;                 // 7,680,000 B
    _Float16* Wt    = (_Float16*)(ws + 7680000);   //    65,536 B
    _Float16* Lt    = (_Float16*)(ws + 7745536);   //    32,768 B

    k_prep<<<256, 256, 0, stream>>>(lin_W, M, Wt, Lt);
    // layer 0 table directly from x (h stays in LDS)
    k_lin_exp_msg<<<NB16, 256, 0, stream>>>(x, Wt, lin_b, Lt, table);
    k_layer<<<NN / 4, 256, 0, stream>>>(table, adj, w, h);
    // layer 1
    k_msg_aux<<<NB16, 256, 0, stream>>>(h, Lt, table);
    k_layer<<<NN / 4, 256, 0, stream>>>(table, adj, w, h);
}

// Round 13
// 113.008 us; speedup vs baseline: 1.1745x; 1.0570x over previous
//
#include <hip/hip_runtime.h>
#include <hip/hip_fp16.h>
#include <math.h>

#define NN 30000
#define KK 32
#define FF 256
#define DD 128
#define NB16 1875   // 30000 / 16 exactly
#define SA 268      // padded f16 row stride for LDS fragment arrays

typedef _Float16 f16x8 __attribute__((ext_vector_type(8)));
typedef _Float16 f16x2 __attribute__((ext_vector_type(2)));
typedef float f32x4v __attribute__((ext_vector_type(4)));

__device__ __forceinline__ float seluf(float x) {
    const float scale = 1.0507009873554804934193349852946f;
    const float alpha = 1.6732632423543772848170429916717f;
    return x > 0.f ? scale * x : scale * alpha * expm1f(x);
}

__device__ __forceinline__ float waveReduceSum(float v) {
#pragma unroll
    for (int m = 1; m < 64; m <<= 1) v += __shfl_xor(v, m, 64);
    return v;
}

// -------- kernel 0: transposed f16 weight tables ---------------------------
__global__ __launch_bounds__(256) void k_prep(
    const float* __restrict__ W, const float* __restrict__ M,
    _Float16* __restrict__ Wt, _Float16* __restrict__ Lt)
{
    const int b = blockIdx.x, t = threadIdx.x;
    if (b < 128) {
        Wt[b * FF + t] = (_Float16)W[t * DD + b];
    } else if (t < 128) {
        const int c = b - 128, k = t;
        const float v = (k == 0 && c == 0) ? 1.f
                      : ((k >= 1 && c >= 1) ? M[(k - 1) * 127 + (c - 1)] : 0.f);
        Lt[c * DD + k] = (_Float16)v;
    }
}

// -------- kernel 1: table0 = msg_aux(normalize(expmap(selu(x@W+b))) @ lw) --
// (unchanged from round 12)
__global__ __launch_bounds__(256) void k_lin_exp_msg(
    const float* __restrict__ x, const _Float16* __restrict__ Wt,
    const float* __restrict__ b, const _Float16* __restrict__ Lt,
    __half* __restrict__ table)
{
    __shared__ _Float16 as_[16][SA];
    __shared__ _Float16 hhi[16][SA];
    __shared__ _Float16 hlo[16][SA];
    __shared__ float red[4][16];
    __shared__ float m0s[16];
    const int wv_ = threadIdx.x >> 6;
    const int lane = threadIdx.x & 63;
    const int g = lane >> 4, c16 = lane & 15;
    const int baseRow = blockIdx.x * 16;
    const int nb = wv_ * 2;
    const int arow = baseRow + c16;

    {
        const float4* xp = (const float4*)(x + (size_t)arow * FF);
#pragma unroll
        for (int i = 0; i < 2; ++i) {
            const int ks = wv_ * 2 + i;
            const float4 f0 = xp[ks * 8 + g * 2];
            const float4 f1 = xp[ks * 8 + g * 2 + 1];
            const float q[8] = {f0.x, f0.y, f0.z, f0.w, f1.x, f1.y, f1.z, f1.w};
            f16x8 a;
#pragma unroll
            for (int j = 0; j < 8; ++j) a[j] = (_Float16)q[j];
            *(f16x8*)&as_[c16][ks * 32 + g * 8] = a;
        }
    }
    __syncthreads();

    f16x8 bw0[8], bw1[8];
#pragma unroll
    for (int ks = 0; ks < 8; ++ks) {
        bw0[ks] = *(const f16x8*)(Wt + (size_t)((nb + 0) * 16 + c16) * FF + ks * 32 + g * 8);
        bw1[ks] = *(const f16x8*)(Wt + (size_t)((nb + 1) * 16 + c16) * FF + ks * 32 + g * 8);
    }
    f16x8 af[8];
#pragma unroll
    for (int ks = 0; ks < 8; ++ks)
        af[ks] = *(const f16x8*)&as_[c16][ks * 32 + g * 8];

    f32x4v acc[2];
    acc[0] = acc[1] = f32x4v{0.f, 0.f, 0.f, 0.f};
#pragma unroll
    for (int ks = 0; ks < 8; ++ks) {
        acc[0] = __builtin_amdgcn_mfma_f32_16x16x32_f16(af[ks], bw0[ks], acc[0], 0, 0, 0);
        acc[1] = __builtin_amdgcn_mfma_f32_16x16x32_f16(af[ks], bw1[ks], acc[1], 0, 0, 0);
    }

    float bias[2];
#pragma unroll
    for (int n = 0; n < 2; ++n) bias[n] = b[(nb + n) * 16 + c16];

    float vv[4][2];
#pragma unroll
    for (int r = 0; r < 4; ++r) {
        float part = 0.f;
#pragma unroll
        for (int n = 0; n < 2; ++n) {
            vv[r][n] = seluf(acc[n][r] + bias[n]);
            float sq = vv[r][n] * vv[r][n];
            if (wv_ == 0 && n == 0 && c16 == 0) sq = 0.f;
            part += sq;
        }
#pragma unroll
        for (int m = 1; m < 16; m <<= 1) part += __shfl_xor(part, m, 64);
        if (c16 == 0) red[wv_][4 * g + r] = part;
    }
    __syncthreads();
#pragma unroll
    for (int r = 0; r < 4; ++r) {
        const int lrow = 4 * g + r;
        const float ldv = red[0][lrow] + red[1][lrow] + red[2][lrow] + red[3][lrow];
        const float nd = sqrtf(fmaxf(ldv + 1e-9f, 1e-10f));
        const float t  = fminf(nd, 1.0f);
        const float sc = sinhf(t) / nd;
        const float tm = sqrtf(1.f + sc * sc * ldv);
#pragma unroll
        for (int n = 0; n < 2; ++n) {
            const int col = (nb + n) * 16 + c16;
            const float o = (wv_ == 0 && n == 0 && c16 == 0) ? tm : sc * vv[r][n];
            const _Float16 hi = (_Float16)o;
            hhi[lrow][col] = hi;
            hlo[lrow][col] = (_Float16)(o - (float)hi);
        }
    }
    __syncthreads();

    f16x8 bl0[4], bl1[4];
#pragma unroll
    for (int ks = 0; ks < 4; ++ks) {
        bl0[ks] = *(const f16x8*)(Lt + (size_t)((nb + 0) * 16 + c16) * DD + ks * 32 + g * 8);
        bl1[ks] = *(const f16x8*)(Lt + (size_t)((nb + 1) * 16 + c16) * DD + ks * 32 + g * 8);
    }
    f16x8 mh[4], ml[4];
#pragma unroll
    for (int ks = 0; ks < 4; ++ks) {
        mh[ks] = *(const f16x8*)&hhi[c16][ks * 32 + g * 8];
        ml[ks] = *(const f16x8*)&hlo[c16][ks * 32 + g * 8];
    }
    acc[0] = acc[1] = f32x4v{0.f, 0.f, 0.f, 0.f};
#pragma unroll
    for (int ks = 0; ks < 4; ++ks) {
        acc[0] = __builtin_amdgcn_mfma_f32_16x16x32_f16(mh[ks], bl0[ks], acc[0], 0, 0, 0);
        acc[0] = __builtin_amdgcn_mfma_f32_16x16x32_f16(ml[ks], bl0[ks], acc[0], 0, 0, 0);
        acc[1] = __builtin_amdgcn_mfma_f32_16x16x32_f16(mh[ks], bl1[ks], acc[1], 0, 0, 0);
        acc[1] = __builtin_amdgcn_mfma_f32_16x16x32_f16(ml[ks], bl1[ks], acc[1], 0, 0, 0);
    }

#pragma unroll
    for (int r = 0; r < 4; ++r) {
        float part = 0.f;
#pragma unroll
        for (int n = 0; n < 2; ++n) {
            float sq = acc[n][r] * acc[n][r];
            if (wv_ == 0 && n == 0 && c16 == 0) sq = 0.f;
            part += sq;
        }
#pragma unroll
        for (int m = 1; m < 16; m <<= 1) part += __shfl_xor(part, m, 64);
        if (c16 == 0) red[wv_][4 * g + r] = part;
        if (wv_ == 0 && c16 == 0) m0s[4 * g + r] = acc[0][r];
    }
    __syncthreads();
#pragma unroll
    for (int r = 0; r < 4; ++r) {
        const int lrow = 4 * g + r;
        const int row = baseRow + lrow;
        const float rn = 1.f / m0s[lrow];
        const float sum2 = red[0][lrow] + red[1][lrow] + red[2][lrow] + red[3][lrow];
        float kn = sum2 * rn * rn;
        kn = fminf(fmaxf(kn, 0.f), 0.9f);
        const float fh = 1.f / sqrtf(1.f - kn);
#pragma unroll
        for (int n = 0; n < 2; ++n) {
            const float val = (wv_ == 0 && n == 0 && c16 == 0) ? fh : acc[n][r] * rn;
            table[(size_t)row * DD + (nb + n) * 16 + c16] = __float2half(val);
        }
    }
}

// -------- kernel 2: fused layer-0 aggregation + layer-1 msg ----------------
// 4 waves x 16 nodes/block. Each wave serially processes 4 nodes (gather +
// hyperbolic mean + activation + normalize, identical math to k_layer),
// writes h rows as exact hi/lo f16 into LDS; then the proven msg-MFMA phase
// produces the layer-1 table. h never touches HBM.
__global__ __launch_bounds__(256) void k_layer_msg(
    const __half* __restrict__ tin, const int* __restrict__ adj,
    const float* __restrict__ w, const _Float16* __restrict__ Lt,
    __half* __restrict__ tout)
{
    __shared__ _Float16 hhi[16][SA];
    __shared__ _Float16 hlo[16][SA];
    __shared__ float red[4][16];
    __shared__ float m0s[16];
    const int wv_ = threadIdx.x >> 6;
    const int lane = threadIdx.x & 63;
    const int g = lane >> 4, c16 = lane & 15;
    const int baseNode = blockIdx.x * 16;

#pragma unroll
    for (int q = 0; q < 4; ++q) {
        const int node = baseNode + wv_ * 4 + q;
        const int   av = adj[node * KK + (lane & 31)];
        const float wvv = w[node * KK + (lane & 31)];

        unsigned int vbits[32];
#pragma unroll
        for (int j = 0; j < KK; ++j) {
            const int idx = __shfl(av, j, 64);
            vbits[j] = *(const unsigned int*)(tin + (size_t)idx * DD + lane * 2);
        }
        const float f = __half2float(tin[(size_t)av * DD]);
        const float lam = wvv * f;
        float ls = lam;
#pragma unroll
        for (int m = 1; m < 32; m <<= 1) ls += __shfl_xor(ls, m, 64);

        float km0 = 0.f, km1 = 0.f;
#pragma unroll
        for (int j = 0; j < KK; ++j) {
            const float cj = __shfl(lam, j, 64);
            const __half2 hh = *(const __half2*)&vbits[j];
            const float2 v = __half22float2(hh);
            km0 = fmaf(cj, v.x, km0);
            km1 = fmaf(cj, v.y, km1);
        }
        const float rl = 1.f / ls;
        const float m0 = km0 * rl;
        const float m1 = km1 * rl;
        float c2 = (lane ? m0 * m0 : 0.f) + m1 * m1;
        const float kn2 = fminf(waveReduceSum(c2), 0.9f);
        const float invs = 1.f / sqrtf(1.f - kn2);
        const float pd = invs + 1.f;
        const float p0 = lane ? seluf(m0 * invs / pd) : 0.f;
        const float p1 = seluf(m1 * invs / pd);
        float pc = p0 * p0 + p1 * p1;
        const float pn = waveReduceSum(pc);
        const float rdn = 1.f / (1.f - pn + 1e-6f);
        const float tm = sqrtf(1.f + 4.f * pn * rdn * rdn);
        const float ox = lane ? 2.f * p0 * rdn : tm;
        const float oy = 2.f * p1 * rdn;
        // write h row (hi/lo exact split) into LDS
        const int lrow = wv_ * 4 + q;
        const _Float16 hx = (_Float16)ox;
        const _Float16 hy = (_Float16)oy;
        f16x2 hi2, lo2;
        hi2[0] = hx; hi2[1] = hy;
        lo2[0] = (_Float16)(ox - (float)hx);
        lo2[1] = (_Float16)(oy - (float)hy);
        *(f16x2*)&hhi[lrow][2 * lane] = hi2;
        *(f16x2*)&hlo[lrow][2 * lane] = lo2;
    }
    __syncthreads();

    // ---- msg phase: tout rows = Klein(msg) + f-header (same as round-12) --
    const int nb = wv_ * 2;
    f16x8 bl0[4], bl1[4];
#pragma unroll
    for (int ks = 0; ks < 4; ++ks) {
        bl0[ks] = *(const f16x8*)(Lt + (size_t)((nb + 0) * 16 + c16) * DD + ks * 32 + g * 8);
        bl1[ks] = *(const f16x8*)(Lt + (size_t)((nb + 1) * 16 + c16) * DD + ks * 32 + g * 8);
    }
    f16x8 mh[4], ml[4];
#pragma unroll
    for (int ks = 0; ks < 4; ++ks) {
        mh[ks] = *(const f16x8*)&hhi[c16][ks * 32 + g * 8];
        ml[ks] = *(const f16x8*)&hlo[c16][ks * 32 + g * 8];
    }
    f32x4v acc[2];
    acc[0] = acc[1] = f32x4v{0.f, 0.f, 0.f, 0.f};
#pragma unroll
    for (int ks = 0; ks < 4; ++ks) {
        acc[0] = __builtin_amdgcn_mfma_f32_16x16x32_f16(mh[ks], bl0[ks], acc[0], 0, 0, 0);
        acc[0] = __builtin_amdgcn_mfma_f32_16x16x32_f16(ml[ks], bl0[ks], acc[0], 0, 0, 0);
        acc[1] = __builtin_amdgcn_mfma_f32_16x16x32_f16(mh[ks], bl1[ks], acc[1], 0, 0, 0);
        acc[1] = __builtin_amdgcn_mfma_f32_16x16x32_f16(ml[ks], bl1[ks], acc[1], 0, 0, 0);
    }

#pragma unroll
    for (int r = 0; r < 4; ++r) {
        float part = 0.f;
#pragma unroll
        for (int n = 0; n < 2; ++n) {
            float sq = acc[n][r] * acc[n][r];
            if (wv_ == 0 && n == 0 && c16 == 0) sq = 0.f;   // time slot
            part += sq;
        }
#pragma unroll
        for (int m = 1; m < 16; m <<= 1) part += __shfl_xor(part, m, 64);
        if (c16 == 0) red[wv_][4 * g + r] = part;
        if (wv_ == 0 && c16 == 0) m0s[4 * g + r] = acc[0][r];
    }
    __syncthreads();
#pragma unroll
    for (int r = 0; r < 4; ++r) {
        const int lrow = 4 * g + r;
        const int row = baseNode + lrow;
        const float rn = 1.f / m0s[lrow];
        const float sum2 = red[0][lrow] + red[1][lrow] + red[2][lrow] + red[3][lrow];
        float kn = sum2 * rn * rn;
        kn = fminf(fmaxf(kn, 0.f), 0.9f);
        const float fh = 1.f / sqrtf(1.f - kn);
#pragma unroll
        for (int n = 0; n < 2; ++n) {
            const float val = (wv_ == 0 && n == 0 && c16 == 0) ? fh : acc[n][r] * rn;
            tout[(size_t)row * DD + (nb + n) * 16 + c16] = __float2half(val);
        }
    }
}

// -------- kernel 3: final gather + mean + activation + normalize -----------
__global__ __launch_bounds__(256) void k_layer(
    const __half* __restrict__ table, const int* __restrict__ adj,
    const float* __restrict__ w, float* __restrict__ out)
{
    const int wave = threadIdx.x >> 6;
    const int lane = threadIdx.x & 63;
    const int node = blockIdx.x * 4 + wave;

    const int   av = adj[node * KK + (lane & 31)];
    const float wv = w[node * KK + (lane & 31)];

    unsigned int vbits[32];
#pragma unroll
    for (int j = 0; j < KK; ++j) {
        const int idx = __shfl(av, j, 64);
        vbits[j] = *(const unsigned int*)(table + (size_t)idx * DD + lane * 2);
    }

    const float f  = __half2float(table[(size_t)av * DD]);
    const float lam = wv * f;
    float ls = lam;
#pragma unroll
    for (int m = 1; m < 32; m <<= 1) ls += __shfl_xor(ls, m, 64);

    float km0 = 0.f, km1 = 0.f;
#pragma unroll
    for (int j = 0; j < KK; ++j) {
        const float cj = __shfl(lam, j, 64);
        const __half2 hh = *(const __half2*)&vbits[j];
        const float2 v = __half22float2(hh);
        km0 = fmaf(cj, v.x, km0);
        km1 = fmaf(cj, v.y, km1);
    }
    const float rl = 1.f / ls;
    const float m0 = km0 * rl;
    const float m1 = km1 * rl;
    float c2 = (lane ? m0 * m0 : 0.f) + m1 * m1;
    const float kn2 = fminf(waveReduceSum(c2), 0.9f);
    const float invs = 1.f / sqrtf(1.f - kn2);
    const float pd = invs + 1.f;
    const float p0 = lane ? seluf(m0 * invs / pd) : 0.f;
    const float p1 = seluf(m1 * invs / pd);
    float pc = p0 * p0 + p1 * p1;
    const float pn = waveReduceSum(pc);
    const float rdn = 1.f / (1.f - pn + 1e-6f);
    const float tm = sqrtf(1.f + 4.f * pn * rdn * rdn);
    float2 o;
    o.x = lane ? 2.f * p0 * rdn : tm;
    o.y = 2.f * p1 * rdn;
    *(float2*)(out + (size_t)node * DD + lane * 2) = o;
}

extern "C" void kernel_launch(void* const* d_in, const int* in_sizes, int n_in,
                              void* d_out, int out_size, void* d_ws, size_t ws_size,
                              hipStream_t stream) {
    const float* x     = (const float*)d_in[0];
    const int*   adj   = (const int*)d_in[1];
    const float* w     = (const float*)d_in[2];
    const float* lin_W = (const float*)d_in[3];
    const float* lin_b = (const float*)d_in[4];
    const float* M     = (const float*)d_in[5];
    float*  out   = (float*)d_out;
    char*   ws    = (char*)d_ws;
    __half*   table0 = (__half*)ws;                  // 7,680,000 B
    __half*   table1 = (__half*)(ws + 7680000);      // 7,680,000 B
    _Float16* Wt     = (_Float16*)(ws + 15360000);   //    65,536 B
    _Float16* Lt     = (_Float16*)(ws + 15425536);   //    32,768 B

    k_prep<<<256, 256, 0, stream>>>(lin_W, M, Wt, Lt);
    k_lin_exp_msg<<<NB16, 256, 0, stream>>>(x, Wt, lin_b, Lt, table0);   // layer-0 table
    k_layer_msg<<<NB16, 256, 0, stream>>>(table0, adj, w, Lt, table1);   // layer-0 agg + layer-1 msg
    k_layer<<<NN / 4, 256, 0, stream>>>(table1, adj, w, out);            // layer-1 agg -> out
}